// Round 8
// baseline (251.606 us; speedup 1.0000x reference)
//
#include <hip/hip_runtime.h>
#include <hip/hip_fp16.h>
#include <float.h>

#define N_NODES   50000
#define N_EDGES   800000
#define INDIM1    128
#define HC        64
#define N_GRAPHS  64
#define NEG_SLOPE 0.2f
#define CAP       64      // slot capacity/node; deg~Poisson(16); validated R5-R14
#define CSTRIDE   16      // cursor: one counter per 64B line (R12: scatter 54->49us)

// Fused layer-1 grid geometry: 3:2 interleave of transform:scatter blocks (R15).
#define FGROUPS   521
#define FTBLK     (3 * FGROUPS)            // 1563 transform blocks
#define FSBLK     (2 * FGROUPS)            // 1042 scatter blocks
#define FGRID     (5 * FGROUPS + 1)        // 2606 total
#define ESTRIDE   (FSBLK * 256)            // 266752 edge stride

// R20: fp16 features (246->236us). R21: 4B CSR entries (lesson: random-scatter
// line amplification is NOT fixable by packing -- L2 evicts before merge; keep
// 4B for the smaller agg-side reads). R22: 4 node-chains/wave in the aggs
// (R3's proven ILP lever, 2->4; R4 lesson respected: VGPR cap stays 128).
typedef _Float16 feat_t;

// ---------------- fused: layer-1 transform + CSR scatter + wedot rider -------
__global__ __launch_bounds__(256, 4) void fused1_kernel(const float* __restrict__ x,
                                                        const float* __restrict__ W,
                                                        const float* __restrict__ att_s,
                                                        const float* __restrict__ att_d,
                                                        feat_t* __restrict__ xs,
                                                        float* __restrict__ a_src,
                                                        float* __restrict__ a_dst,
                                                        const int* __restrict__ src,
                                                        const int* __restrict__ dst,
                                                        const float* __restrict__ eattr,
                                                        int* __restrict__ cursor,
                                                        unsigned int* __restrict__ csr_se,
                                                        const float* __restrict__ We1,
                                                        const float* __restrict__ ae1,
                                                        const float* __restrict__ We2,
                                                        const float* __restrict__ ae2,
                                                        float* __restrict__ wd) {
    constexpr int K4 = INDIM1 / 4;
    constexpr int NPW = 8;
    __shared__ float4 Wsh[K4 * 64];       // [k4][col]: 32KB
    __shared__ float4 xsh[4][2][K4];      // [wave][node-in-pair][k4]
    int bid = blockIdx.x;
    int t = threadIdx.x;

    if (bid == FGRID - 1) {
        // wedot rider block (R13-validated)
        if (t < 128) {
            const float* We = (t < 64) ? We1 : We2;
            const float* ae = (t < 64) ? ae1 : ae2;
            int l = t & 63;
            float p = We[l] * ae[l];
            for (int off = 1; off < 16; off <<= 1) p += __shfl_xor(p, off);
            if ((l & 15) == 0) wd[(t >> 6) * 4 + (l >> 4)] = p;
        }
        return;
    }

    int grp = bid / 5;
    int rem = bid - grp * 5;
    if (rem >= 3) {
        // ---- scatter path (block-uniform branch; returns before syncthreads)
        int sb = grp * 2 + (rem - 3);     // 0..1041
        for (int e = sb * 256 + t; e < N_EDGES; e += ESTRIDE) {
            int d = dst[e];
            int c = atomicAdd(&cursor[(size_t)d * CSTRIDE], 1);
            if (c < CAP) {
                unsigned int pk = (unsigned int)(src[e] & 0xFFFF)
                                | ((unsigned int)__half_as_ushort(__float2half(eattr[e])) << 16);
                csr_se[(size_t)d * CAP + c] = pk;
            }
        }
        return;
    }

    // ---- transform path, block id 0..1562
    int tb = grp * 3 + rem;
    for (int i = t; i < K4 * 64; i += 256) {
        int k4 = i >> 6, col = i & 63;
        Wsh[i] = make_float4(W[(4 * k4 + 0) * 64 + col], W[(4 * k4 + 1) * 64 + col],
                             W[(4 * k4 + 2) * 64 + col], W[(4 * k4 + 3) * 64 + col]);
    }
    __syncthreads();
    int w = t >> 6, lane = t & 63;
    float avs = att_s[lane], avd = att_d[lane];
    int node0 = tb * (4 * NPW) + w * NPW;
    for (int ng = 0; ng < NPW; ng += 2) {
        int nbase = node0 + ng;
        if (nbase >= N_NODES) return;     // wave-uniform
        for (int q = lane; q < 2 * K4; q += 64) {
            int nn = q / K4, kk = q - nn * K4;
            int node = nbase + nn;
            xsh[w][nn][kk] = (node < N_NODES)
                ? ((const float4*)(x + (size_t)node * INDIM1))[kk]
                : make_float4(0.f, 0.f, 0.f, 0.f);
        }
        float acc0 = 0.f, acc1 = 0.f;
#pragma unroll 4
        for (int k4 = 0; k4 < K4; ++k4) {
            float4 wv = Wsh[k4 * 64 + lane];          // 1 b128 read feeds 8 fmas
            float4 x0 = xsh[w][0][k4];
            float4 x1 = xsh[w][1][k4];
            acc0 = fmaf(x0.x, wv.x, acc0);
            acc0 = fmaf(x0.y, wv.y, acc0);
            acc0 = fmaf(x0.z, wv.z, acc0);
            acc0 = fmaf(x0.w, wv.w, acc0);
            acc1 = fmaf(x1.x, wv.x, acc1);
            acc1 = fmaf(x1.y, wv.y, acc1);
            acc1 = fmaf(x1.z, wv.z, acc1);
            acc1 = fmaf(x1.w, wv.w, acc1);
        }
#pragma unroll
        for (int nn = 0; nn < 2; ++nn) {
            int node = nbase + nn;
            if (node >= N_NODES) break;
            float a = nn ? acc1 : acc0;
            xs[(size_t)node * 64 + lane] = (feat_t)a;
            float ps = a * avs;
            float pd = a * avd;
            for (int off = 1; off < 16; off <<= 1) {
                ps += __shfl_xor(ps, off);
                pd += __shfl_xor(pd, off);
            }
            if ((lane & 15) == 0) {
                a_src[node * 4 + (lane >> 4)] = ps;
                a_dst[node * 4 + (lane >> 4)] = pd;
            }
        }
    }
}

// Common per-node chain macros for the aggs (named vars, no runtime arrays).
#define ALPHA(SUF)                                                              \
    {                                                                           \
        int j = beg##SUF + it * 16 + e_idx;                                     \
        bool v = j < end##SUF;                                                  \
        sv##SUF = 0;                                                            \
        float a = -FLT_MAX;                                                     \
        if (v) {                                                                \
            unsigned int se = csr_se[j];                                        \
            sv##SUF = (int)(se & 0xFFFFu);                                      \
            float ea = __half2float(__ushort_as_half((unsigned short)(se >> 16)));\
            float as = a_src[sv##SUF * 4 + h4];                                 \
            a = as + adv##SUF + ea * wdv;                                       \
            a = a > 0.f ? a : NEG_SLOPE * a;                                    \
        }                                                                       \
        float cm = a;                                                           \
        cm = fmaxf(cm, __shfl_xor(cm, 4));                                      \
        cm = fmaxf(cm, __shfl_xor(cm, 8));                                      \
        cm = fmaxf(cm, __shfl_xor(cm, 16));                                     \
        cm = fmaxf(cm, __shfl_xor(cm, 32));                                     \
        float mn = fmaxf(m##SUF, cm);                                           \
        float sc = __expf(m##SUF - mn);                                         \
        wgt##SUF = __expf(a - mn);                                              \
        s##SUF = s##SUF * sc + wgt##SUF;                                        \
        m##SUF = mn;                                                            \
        acc##SUF *= __shfl(sc, h2);                                             \
    }

#define GATHER(SUF)                                                             \
    {                                                                           \
        _Pragma("unroll")                                                       \
        for (int e = 0; e < 16; ++e) {                                          \
            int svb = __builtin_amdgcn_readlane(sv##SUF, e << 2);               \
            float wg = __shfl(wgt##SUF, (e << 2) | h2);                         \
            acc##SUF = fmaf(wg, (float)xs[(size_t)svb * 64 + lane], acc##SUF);  \
        }                                                                       \
    }

#define FINISH(SUF, RES)                                                        \
    {                                                                           \
        float s = s##SUF;                                                       \
        s += __shfl_xor(s, 4);                                                  \
        s += __shfl_xor(s, 8);                                                  \
        s += __shfl_xor(s, 16);                                                 \
        s += __shfl_xor(s, 32);                                                 \
        float sh = __shfl(s, h2);                                               \
        RES = ((sh > 0.f) ? acc##SUF / sh : 0.f) + bv;                          \
    }

// ---------------- agg1 + fused layer-2 transform (R22: 4 chains/wave) --------
__global__ __launch_bounds__(256, 4) void agg1_kernel(const feat_t* __restrict__ xs,
                                                      const unsigned int* __restrict__ csr_se,
                                                      const int* __restrict__ degp,
                                                      const float* __restrict__ a_src,
                                                      const float* __restrict__ a_dst,
                                                      const float* __restrict__ wd,
                                                      const float* __restrict__ bias,
                                                      const float* __restrict__ W2,
                                                      const float* __restrict__ as2,
                                                      const float* __restrict__ ad2,
                                                      feat_t* __restrict__ xs2,
                                                      float* __restrict__ asrc2,
                                                      float* __restrict__ adst2) {
    __shared__ float W2sh[64 * 64];       // 16KB
    __shared__ float hsh[4][4][64];       // 4KB: [wave][node][ch]
    int t = threadIdx.x;
    // stage W2 early; no barrier until after the gather loop
#pragma unroll
    for (int i = 0; i < 4; ++i)
        ((float4*)W2sh)[t + 256 * i] = ((const float4*)W2)[t + 256 * i];

    int w = t >> 6, lane = t & 63;
    const int e_idx = lane >> 2;
    const int h4 = lane & 3;
    const int h2 = lane >> 4;
    int nodeA = blockIdx.x * 16 + w * 4;   // 3125*16 == N_NODES exactly
    int nodeB = nodeA + 1, nodeC = nodeA + 2, nodeD = nodeA + 3;

    float wdv = wd[h4];
    float bv = bias[lane];
    float avs2 = as2[lane], avd2 = ad2[lane];
    float advA = a_dst[nodeA * 4 + h4];
    float advB = a_dst[nodeB * 4 + h4];
    float advC = a_dst[nodeC * 4 + h4];
    float advD = a_dst[nodeD * 4 + h4];
    int nA = min(degp[(size_t)nodeA * CSTRIDE], CAP);
    int nB = min(degp[(size_t)nodeB * CSTRIDE], CAP);
    int nC = min(degp[(size_t)nodeC * CSTRIDE], CAP);
    int nD = min(degp[(size_t)nodeD * CSTRIDE], CAP);
    int begA = nodeA * CAP, endA = begA + nA;
    int begB = nodeB * CAP, endB = begB + nB;
    int begC = nodeC * CAP, endC = begC + nC;
    int begD = nodeD * CAP, endD = begD + nD;

    float mA = -FLT_MAX, sA = 0.f, accA = 0.f;
    float mB = -FLT_MAX, sB = 0.f, accB = 0.f;
    float mC = -FLT_MAX, sC = 0.f, accC = 0.f;
    float mD = -FLT_MAX, sD = 0.f, accD = 0.f;

    int itA = (nA + 15) >> 4, itB = (nB + 15) >> 4;
    int itC_ = (nC + 15) >> 4, itD = (nD + 15) >> 4;
    int itMin = min(min(itA, itB), min(itC_, itD));

    for (int it = 0; it < itMin; ++it) {
        int svA, svB, svC, svD; float wgtA, wgtB, wgtC, wgtD;
        ALPHA(A) ALPHA(B) ALPHA(C) ALPHA(D)
        GATHER(A) GATHER(B) GATHER(C) GATHER(D)
    }
    for (int it = itMin; it < itA; ++it) { int svA; float wgtA; ALPHA(A) GATHER(A) }
    for (int it = itMin; it < itB; ++it) { int svB; float wgtB; ALPHA(B) GATHER(B) }
    for (int it = itMin; it < itC_; ++it) { int svC; float wgtC; ALPHA(C) GATHER(C) }
    for (int it = itMin; it < itD; ++it) { int svD; float wgtD; ALPHA(D) GATHER(D) }

    float resA, resB, resC, resD;
    FINISH(A, resA) FINISH(B, resB) FINISH(C, resC) FINISH(D, resD)
    // h = relu(layer1_out + b1)
    float hA = fmaxf(resA, 0.f), hB = fmaxf(resB, 0.f);
    float hC = fmaxf(resC, 0.f), hD = fmaxf(resD, 0.f);

    hsh[w][0][lane] = hA;
    hsh[w][1][lane] = hB;
    hsh[w][2][lane] = hC;
    hsh[w][3][lane] = hD;
    __syncthreads();                      // W2sh complete; all 256 reach this

    float acc2A = 0.f, acc2B = 0.f, acc2C = 0.f, acc2D = 0.f;
#pragma unroll
    for (int k4 = 0; k4 < 16; ++k4) {
        float4 ha = ((const float4*)hsh[w][0])[k4];   // wave-broadcast
        float4 hb = ((const float4*)hsh[w][1])[k4];
        float4 hc = ((const float4*)hsh[w][2])[k4];
        float4 hd = ((const float4*)hsh[w][3])[k4];
        float w0 = W2sh[(4 * k4 + 0) * 64 + lane];
        float w1 = W2sh[(4 * k4 + 1) * 64 + lane];
        float w2 = W2sh[(4 * k4 + 2) * 64 + lane];
        float w3 = W2sh[(4 * k4 + 3) * 64 + lane];
        acc2A = fmaf(ha.x, w0, acc2A); acc2B = fmaf(hb.x, w0, acc2B);
        acc2C = fmaf(hc.x, w0, acc2C); acc2D = fmaf(hd.x, w0, acc2D);
        acc2A = fmaf(ha.y, w1, acc2A); acc2B = fmaf(hb.y, w1, acc2B);
        acc2C = fmaf(hc.y, w1, acc2C); acc2D = fmaf(hd.y, w1, acc2D);
        acc2A = fmaf(ha.z, w2, acc2A); acc2B = fmaf(hb.z, w2, acc2B);
        acc2C = fmaf(hc.z, w2, acc2C); acc2D = fmaf(hd.z, w2, acc2D);
        acc2A = fmaf(ha.w, w3, acc2A); acc2B = fmaf(hb.w, w3, acc2B);
        acc2C = fmaf(hc.w, w3, acc2C); acc2D = fmaf(hd.w, w3, acc2D);
    }
    xs2[(size_t)nodeA * 64 + lane] = (feat_t)acc2A;
    xs2[(size_t)nodeB * 64 + lane] = (feat_t)acc2B;
    xs2[(size_t)nodeC * 64 + lane] = (feat_t)acc2C;
    xs2[(size_t)nodeD * 64 + lane] = (feat_t)acc2D;
    float psA = acc2A * avs2, pdA = acc2A * avd2;
    float psB = acc2B * avs2, pdB = acc2B * avd2;
    float psC = acc2C * avs2, pdC = acc2C * avd2;
    float psD = acc2D * avs2, pdD = acc2D * avd2;
    for (int off = 1; off < 16; off <<= 1) {
        psA += __shfl_xor(psA, off); pdA += __shfl_xor(pdA, off);
        psB += __shfl_xor(psB, off); pdB += __shfl_xor(pdB, off);
        psC += __shfl_xor(psC, off); pdC += __shfl_xor(pdC, off);
        psD += __shfl_xor(psD, off); pdD += __shfl_xor(pdD, off);
    }
    if ((lane & 15) == 0) {
        int q = lane >> 4;
        asrc2[nodeA * 4 + q] = psA; adst2[nodeA * 4 + q] = pdA;
        asrc2[nodeB * 4 + q] = psB; adst2[nodeB * 4 + q] = pdB;
        asrc2[nodeC * 4 + q] = psC; adst2[nodeC * 4 + q] = pdC;
        asrc2[nodeD * 4 + q] = psD; adst2[nodeD * 4 + q] = pdD;
    }
}

// ---------------- agg2 + fused mean-pool (R22: 4 chains/wave) ----------------
__global__ __launch_bounds__(256, 4) void agg2_kernel(const feat_t* __restrict__ xs,
                                                      const unsigned int* __restrict__ csr_se,
                                                      const int* __restrict__ degp,
                                                      const float* __restrict__ a_src,
                                                      const float* __restrict__ a_dst,
                                                      const float* __restrict__ wd,
                                                      const float* __restrict__ bias,
                                                      const int* __restrict__ batch,
                                                      float* __restrict__ gout) {
    __shared__ float plds[256];
    int t = threadIdx.x;
    int w = t >> 6, lane = t & 63;
    const int e_idx = lane >> 2;
    const int h4 = lane & 3;
    const int h2 = lane >> 4;
    int nodeA = blockIdx.x * 16 + w * 4;   // 3125*16 == N_NODES exactly
    int nodeB = nodeA + 1, nodeC = nodeA + 2, nodeD = nodeA + 3;

    float wdv = wd[h4];
    float bv = bias[lane];
    float advA = a_dst[nodeA * 4 + h4];
    float advB = a_dst[nodeB * 4 + h4];
    float advC = a_dst[nodeC * 4 + h4];
    float advD = a_dst[nodeD * 4 + h4];
    int nA = min(degp[(size_t)nodeA * CSTRIDE], CAP);
    int nB = min(degp[(size_t)nodeB * CSTRIDE], CAP);
    int nC = min(degp[(size_t)nodeC * CSTRIDE], CAP);
    int nD = min(degp[(size_t)nodeD * CSTRIDE], CAP);
    int begA = nodeA * CAP, endA = begA + nA;
    int begB = nodeB * CAP, endB = begB + nB;
    int begC = nodeC * CAP, endC = begC + nC;
    int begD = nodeD * CAP, endD = begD + nD;

    float mA = -FLT_MAX, sA = 0.f, accA = 0.f;
    float mB = -FLT_MAX, sB = 0.f, accB = 0.f;
    float mC = -FLT_MAX, sC = 0.f, accC = 0.f;
    float mD = -FLT_MAX, sD = 0.f, accD = 0.f;

    int itA = (nA + 15) >> 4, itB = (nB + 15) >> 4;
    int itC_ = (nC + 15) >> 4, itD = (nD + 15) >> 4;
    int itMin = min(min(itA, itB), min(itC_, itD));

    for (int it = 0; it < itMin; ++it) {
        int svA, svB, svC, svD; float wgtA, wgtB, wgtC, wgtD;
        ALPHA(A) ALPHA(B) ALPHA(C) ALPHA(D)
        GATHER(A) GATHER(B) GATHER(C) GATHER(D)
    }
    for (int it = itMin; it < itA; ++it) { int svA; float wgtA; ALPHA(A) GATHER(A) }
    for (int it = itMin; it < itB; ++it) { int svB; float wgtB; ALPHA(B) GATHER(B) }
    for (int it = itMin; it < itC_; ++it) { int svC; float wgtC; ALPHA(C) GATHER(C) }
    for (int it = itMin; it < itD; ++it) { int svD; float wgtD; ALPHA(D) GATHER(D) }

    float resA, resB, resC, resD;
    FINISH(A, resA) FINISH(B, resB) FINISH(C, resC) FINISH(D, resD)

    int gF = batch[blockIdx.x * 16];
    int gL = batch[blockIdx.x * 16 + 15];
    if (gF == gL) {                             // block-uniform branch (common)
        plds[w * 64 + lane] = resA + resB + resC + resD;
        __syncthreads();
        if (w == 0) {
            float v = plds[lane] + plds[64 + lane] +
                      plds[128 + lane] + plds[192 + lane];
            atomicAdd(&gout[gF * 64 + lane], v);
        }
    } else {
        int gA = batch[nodeA], gB = batch[nodeB];
        int gC = batch[nodeC], gD = batch[nodeD];
        float cur = resA; int gcur = gA;
        if (gB == gcur) cur += resB;
        else { atomicAdd(&gout[gcur * 64 + lane], cur); gcur = gB; cur = resB; }
        if (gC == gcur) cur += resC;
        else { atomicAdd(&gout[gcur * 64 + lane], cur); gcur = gC; cur = resC; }
        if (gD == gcur) cur += resD;
        else { atomicAdd(&gout[gcur * 64 + lane], cur); gcur = gD; cur = resD; }
        atomicAdd(&gout[gcur * 64 + lane], cur);
    }
}

__global__ void pool_div_kernel(float* __restrict__ out, const int* __restrict__ batch) {
    int g = blockIdx.x, t = threadIdx.x;
    int lo = 0, hi = N_NODES;
    while (lo < hi) { int mid = (lo + hi) >> 1; if (batch[mid] < g) lo = mid + 1; else hi = mid; }
    int lo2 = lo, hi2 = N_NODES;
    while (lo2 < hi2) { int mid = (lo2 + hi2) >> 1; if (batch[mid] <= g) lo2 = mid + 1; else hi2 = mid; }
    float c = (float)max(lo2 - lo, 1);
    out[g * 64 + t] /= c;
}

// ---------------- launch ----------------

extern "C" void kernel_launch(void* const* d_in, const int* in_sizes, int n_in,
                              void* d_out, int out_size, void* d_ws, size_t ws_size,
                              hipStream_t stream) {
    const float* x    = (const float*)d_in[0];
    const int*   eidx = (const int*)d_in[1];
    const float* eat  = (const float*)d_in[2];
    const int*   batch= (const int*)d_in[3];
    const float* W1   = (const float*)d_in[4];
    const float* We1  = (const float*)d_in[5];
    const float* as1  = (const float*)d_in[6];
    const float* ad1  = (const float*)d_in[7];
    const float* ae1  = (const float*)d_in[8];
    const float* b1   = (const float*)d_in[9];
    const float* W2   = (const float*)d_in[10];
    const float* We2  = (const float*)d_in[11];
    const float* as2  = (const float*)d_in[12];
    const float* ad2  = (const float*)d_in[13];
    const float* ae2  = (const float*)d_in[14];
    const float* b2   = (const float*)d_in[15];
    const int* src  = eidx;             // edge_index[0]
    const int* dstp = eidx + N_EDGES;   // edge_index[1]
    float* out = (float*)d_out;

    char* p = (char*)d_ws;
    auto alloc = [&](size_t bytes) {
        char* r = p;
        p += (bytes + 255) & ~(size_t)255;
        return r;
    };
    unsigned int* csrse = (unsigned int*)alloc((size_t)N_NODES * CAP * 4);  // 12.8 MB
    feat_t* xs     = (feat_t*)alloc((size_t)N_NODES * 64 * 2);     // 6.4 MB fp16
    feat_t* hbuf   = (feat_t*)alloc((size_t)N_NODES * 64 * 2);     // 6.4 MB fp16
    float*  asrc   = (float*)alloc((size_t)N_NODES * 4 * 4);
    float*  adst   = (float*)alloc((size_t)N_NODES * 4 * 4);
    float*  asrc2  = (float*)alloc((size_t)N_NODES * 4 * 4);
    float*  adst2  = (float*)alloc((size_t)N_NODES * 4 * 4);
    float*  wd     = (float*)alloc(64);                            // wd1[4] || wd2[4]
    int*    cursor = (int*)alloc((size_t)N_NODES * CSTRIDE * 4);   // 3.2 MB padded

    hipMemsetAsync(cursor, 0, (size_t)N_NODES * CSTRIDE * 4, stream);
    hipMemsetAsync(d_out, 0, (size_t)N_GRAPHS * 64 * 4, stream);

    const int NB = N_NODES / 16;                           // 3125 (×16 == N_NODES)

    // layer 1: fused transform + CSR scatter + wedot rider (R15)
    fused1_kernel<<<FGRID, 256, 0, stream>>>(x, W1, as1, ad1, xs, asrc, adst,
                                             src, dstp, eat, cursor, csrse,
                                             We1, ae1, We2, ae2, wd);
    // aggregate layer 1 + fused layer-2 transform (R22: 4 chains/wave)
    agg1_kernel<<<NB, 256, 0, stream>>>(xs, csrse, cursor, asrc, adst,
                                        wd, b1, W2, as2, ad2,
                                        hbuf, asrc2, adst2);
    // aggregate layer 2 + fused mean-pool (R22: 4 chains/wave)
    agg2_kernel<<<NB, 256, 0, stream>>>(hbuf, csrse, cursor, asrc2, adst2,
                                        wd + 4, b2, batch, out);
    pool_div_kernel<<<N_GRAPHS, 64, 0, stream>>>(out, batch);
}

// Round 9
// 235.671 us; speedup vs baseline: 1.0676x; 1.0676x over previous
//
#include <hip/hip_runtime.h>
#include <hip/hip_fp16.h>
#include <float.h>

#define N_NODES   50000
#define N_EDGES   800000
#define INDIM1    128
#define HC        64
#define N_GRAPHS  64
#define NEG_SLOPE 0.2f
#define CAP       64      // slot capacity/node; deg~Poisson(16); validated R5-R14
#define CSTRIDE   16      // cursor: one counter per 64B line (R12: scatter 54->49us)

// Fused layer-1 grid geometry: 3:2 interleave of transform:scatter blocks (R15).
#define FGROUPS   521
#define FTBLK     (3 * FGROUPS)            // 1563 transform blocks
#define FSBLK     (2 * FGROUPS)            // 1042 scatter blocks
#define FGRID     (5 * FGROUPS + 1)        // 2606 total
#define ESTRIDE   (FSBLK * 256)            // 266752 edge stride; 3*ESTRIDE covers N_EDGES

// R20: fp16 features (246->236). R21: 4B CSR entries (233.7). R22 LESSON: 4
// node-chains/wave regressed (compiler allocs 64 VGPR and serializes; tails
// dominate at deg~16) -- 2 chains is the schedulable sweet spot. R23: scatter
// 3x manual unroll (loads->atomics->stores batched; the scatter leg had ILP 1)
// + d_out zeroing folded into the rider block.
typedef _Float16 feat_t;

// ---------------- fused: layer-1 transform + CSR scatter + wedot rider -------
__global__ __launch_bounds__(256, 4) void fused1_kernel(const float* __restrict__ x,
                                                        const float* __restrict__ W,
                                                        const float* __restrict__ att_s,
                                                        const float* __restrict__ att_d,
                                                        feat_t* __restrict__ xs,
                                                        float* __restrict__ a_src,
                                                        float* __restrict__ a_dst,
                                                        const int* __restrict__ src,
                                                        const int* __restrict__ dst,
                                                        const float* __restrict__ eattr,
                                                        int* __restrict__ cursor,
                                                        unsigned int* __restrict__ csr_se,
                                                        const float* __restrict__ We1,
                                                        const float* __restrict__ ae1,
                                                        const float* __restrict__ We2,
                                                        const float* __restrict__ ae2,
                                                        float* __restrict__ wd,
                                                        float* __restrict__ gout) {
    constexpr int K4 = INDIM1 / 4;
    constexpr int NPW = 8;
    __shared__ float4 Wsh[K4 * 64];       // [k4][col]: 32KB
    __shared__ float4 xsh[4][2][K4];      // [wave][node-in-pair][k4]
    int bid = blockIdx.x;
    int t = threadIdx.x;

    if (bid == FGRID - 1) {
        // wedot rider block (R13) + gout zeroing (R23: replaces a memset dispatch;
        // stream order guarantees completion before agg2's atomics).
        if (t < 128) {
            const float* We = (t < 64) ? We1 : We2;
            const float* ae = (t < 64) ? ae1 : ae2;
            int l = t & 63;
            float p = We[l] * ae[l];
            for (int off = 1; off < 16; off <<= 1) p += __shfl_xor(p, off);
            if ((l & 15) == 0) wd[(t >> 6) * 4 + (l >> 4)] = p;
        } else {
            for (int i = t - 128; i < N_GRAPHS * 64; i += 128) gout[i] = 0.f;
        }
        return;
    }

    int grp = bid / 5;
    int rem = bid - grp * 5;
    if (rem >= 3) {
        // ---- scatter path, 3x unrolled (block-uniform; returns pre-barrier).
        // e0,e1 provably < N_EDGES (max 533503); only e2 needs the check.
        int sb = grp * 2 + (rem - 3);     // 0..1041
        int e0 = sb * 256 + t;
        int e1 = e0 + ESTRIDE;
        int e2 = e1 + ESTRIDE;
        bool v2 = e2 < N_EDGES;
        int d0 = dst[e0], d1 = dst[e1], d2 = v2 ? dst[e2] : 0;
        int s0 = src[e0], s1 = src[e1], s2 = v2 ? src[e2] : 0;
        float a0 = eattr[e0], a1 = eattr[e1], a2 = v2 ? eattr[e2] : 0.f;
        int c0 = atomicAdd(&cursor[(size_t)d0 * CSTRIDE], 1);
        int c1 = atomicAdd(&cursor[(size_t)d1 * CSTRIDE], 1);
        int c2 = v2 ? atomicAdd(&cursor[(size_t)d2 * CSTRIDE], 1) : CAP;
        unsigned int pk0 = (unsigned int)(s0 & 0xFFFF)
                         | ((unsigned int)__half_as_ushort(__float2half(a0)) << 16);
        unsigned int pk1 = (unsigned int)(s1 & 0xFFFF)
                         | ((unsigned int)__half_as_ushort(__float2half(a1)) << 16);
        unsigned int pk2 = (unsigned int)(s2 & 0xFFFF)
                         | ((unsigned int)__half_as_ushort(__float2half(a2)) << 16);
        if (c0 < CAP) csr_se[(size_t)d0 * CAP + c0] = pk0;
        if (c1 < CAP) csr_se[(size_t)d1 * CAP + c1] = pk1;
        if (c2 < CAP) csr_se[(size_t)d2 * CAP + c2] = pk2;
        return;
    }

    // ---- transform path, block id 0..1562
    int tb = grp * 3 + rem;
    for (int i = t; i < K4 * 64; i += 256) {
        int k4 = i >> 6, col = i & 63;
        Wsh[i] = make_float4(W[(4 * k4 + 0) * 64 + col], W[(4 * k4 + 1) * 64 + col],
                             W[(4 * k4 + 2) * 64 + col], W[(4 * k4 + 3) * 64 + col]);
    }
    __syncthreads();
    int w = t >> 6, lane = t & 63;
    float avs = att_s[lane], avd = att_d[lane];
    int node0 = tb * (4 * NPW) + w * NPW;
    for (int ng = 0; ng < NPW; ng += 2) {
        int nbase = node0 + ng;
        if (nbase >= N_NODES) return;     // wave-uniform
        for (int q = lane; q < 2 * K4; q += 64) {
            int nn = q / K4, kk = q - nn * K4;
            int node = nbase + nn;
            xsh[w][nn][kk] = (node < N_NODES)
                ? ((const float4*)(x + (size_t)node * INDIM1))[kk]
                : make_float4(0.f, 0.f, 0.f, 0.f);
        }
        float acc0 = 0.f, acc1 = 0.f;
#pragma unroll 4
        for (int k4 = 0; k4 < K4; ++k4) {
            float4 wv = Wsh[k4 * 64 + lane];          // 1 b128 read feeds 8 fmas
            float4 x0 = xsh[w][0][k4];
            float4 x1 = xsh[w][1][k4];
            acc0 = fmaf(x0.x, wv.x, acc0);
            acc0 = fmaf(x0.y, wv.y, acc0);
            acc0 = fmaf(x0.z, wv.z, acc0);
            acc0 = fmaf(x0.w, wv.w, acc0);
            acc1 = fmaf(x1.x, wv.x, acc1);
            acc1 = fmaf(x1.y, wv.y, acc1);
            acc1 = fmaf(x1.z, wv.z, acc1);
            acc1 = fmaf(x1.w, wv.w, acc1);
        }
#pragma unroll
        for (int nn = 0; nn < 2; ++nn) {
            int node = nbase + nn;
            if (node >= N_NODES) break;
            float a = nn ? acc1 : acc0;
            xs[(size_t)node * 64 + lane] = (feat_t)a;
            float ps = a * avs;
            float pd = a * avd;
            for (int off = 1; off < 16; off <<= 1) {
                ps += __shfl_xor(ps, off);
                pd += __shfl_xor(pd, off);
            }
            if ((lane & 15) == 0) {
                a_src[node * 4 + (lane >> 4)] = ps;
                a_dst[node * 4 + (lane >> 4)] = pd;
            }
        }
    }
}

// ---------------- agg1 + fused layer-2 transform (R19/R7-proven, 2 chains) ---
__global__ __launch_bounds__(256, 4) void agg1_kernel(const feat_t* __restrict__ xs,
                                                      const unsigned int* __restrict__ csr_se,
                                                      const int* __restrict__ degp,
                                                      const float* __restrict__ a_src,
                                                      const float* __restrict__ a_dst,
                                                      const float* __restrict__ wd,
                                                      const float* __restrict__ bias,
                                                      const float* __restrict__ W2,
                                                      const float* __restrict__ as2,
                                                      const float* __restrict__ ad2,
                                                      feat_t* __restrict__ xs2,
                                                      float* __restrict__ asrc2,
                                                      float* __restrict__ adst2) {
    __shared__ float W2sh[64 * 64];       // 16KB
    __shared__ float hshA[4][64];
    __shared__ float hshB[4][64];
    int t = threadIdx.x;
    // stage W2 early; no barrier until after the gather loop
#pragma unroll
    for (int i = 0; i < 4; ++i)
        ((float4*)W2sh)[t + 256 * i] = ((const float4*)W2)[t + 256 * i];

    int w = t >> 6, lane = t & 63;
    const int e_idx = lane >> 2;
    const int h4 = lane & 3;
    const int h2 = lane >> 4;
    int nodeA = blockIdx.x * 8 + w * 2;    // 6250*8 == N_NODES exactly
    int nodeB = nodeA + 1;

    float wdv = wd[h4];
    float bv = bias[lane];
    float avs2 = as2[lane], avd2 = ad2[lane];
    float advA = a_dst[nodeA * 4 + h4];
    float advB = a_dst[nodeB * 4 + h4];
    int nA = min(degp[(size_t)nodeA * CSTRIDE], CAP);
    int nB = min(degp[(size_t)nodeB * CSTRIDE], CAP);
    int begA = nodeA * CAP, endA = begA + nA;
    int begB = nodeB * CAP, endB = begB + nB;

    float mA = -FLT_MAX, sA = 0.f, accA = 0.f;
    float mB = -FLT_MAX, sB = 0.f, accB = 0.f;

    auto alpha_phase = [&](int beg, int end, int it, float adv,
                           float& m, float& s, float& acc, int& sv, float& wgt) {
        int j = beg + it * 16 + e_idx;
        bool v = j < end;
        sv = 0;
        float a = -FLT_MAX;
        if (v) {
            unsigned int se = csr_se[j];
            sv = (int)(se & 0xFFFFu);
            float ea = __half2float(__ushort_as_half((unsigned short)(se >> 16)));
            float as = a_src[sv * 4 + h4];          // gather, 800KB L2-resident
            a = as + adv + ea * wdv;
            a = a > 0.f ? a : NEG_SLOPE * a;
        }
        float cm = a;
        cm = fmaxf(cm, __shfl_xor(cm, 4));
        cm = fmaxf(cm, __shfl_xor(cm, 8));
        cm = fmaxf(cm, __shfl_xor(cm, 16));
        cm = fmaxf(cm, __shfl_xor(cm, 32));
        float mn = fmaxf(m, cm);
        float sc = __expf(m - mn);
        wgt = __expf(a - mn);                       // 0 for invalid slots
        s = s * sc + wgt;
        m = mn;
        acc *= __shfl(sc, h2);
    };
    auto gather_phase = [&](int sv, float wgt, float& acc) {
#pragma unroll
        for (int e = 0; e < 16; ++e) {
            int svb = __builtin_amdgcn_readlane(sv, e << 2);   // SGPR row index
            float wg = __shfl(wgt, (e << 2) | h2);
            acc = fmaf(wg, (float)xs[(size_t)svb * 64 + lane], acc);
        }
    };

    int itA = (nA + 15) >> 4, itB = (nB + 15) >> 4;
    int itC = min(itA, itB);
    for (int it = 0; it < itC; ++it) {
        int svA, svB; float wgtA, wgtB;
        alpha_phase(begA, endA, it, advA, mA, sA, accA, svA, wgtA);
        alpha_phase(begB, endB, it, advB, mB, sB, accB, svB, wgtB);
        gather_phase(svA, wgtA, accA);
        gather_phase(svB, wgtB, accB);
    }
    for (int it = itC; it < itA; ++it) {
        int svA; float wgtA;
        alpha_phase(begA, endA, it, advA, mA, sA, accA, svA, wgtA);
        gather_phase(svA, wgtA, accA);
    }
    for (int it = itC; it < itB; ++it) {
        int svB; float wgtB;
        alpha_phase(begB, endB, it, advB, mB, sB, accB, svB, wgtB);
        gather_phase(svB, wgtB, accB);
    }

    auto finish = [&](float s, float acc) {
        s += __shfl_xor(s, 4);
        s += __shfl_xor(s, 8);
        s += __shfl_xor(s, 16);
        s += __shfl_xor(s, 32);
        float sh = __shfl(s, h2);
        float res = (sh > 0.f) ? acc / sh : 0.f;
        return res + bv;
    };
    // h = relu(layer1_out + b1)
    float hA = fmaxf(finish(sA, accA), 0.f);
    float hB = fmaxf(finish(sB, accB), 0.f);

    hshA[w][lane] = hA;
    hshB[w][lane] = hB;
    __syncthreads();                      // W2sh complete; all 256 reach this

    float acc2A = 0.f, acc2B = 0.f;
#pragma unroll
    for (int k4 = 0; k4 < 16; ++k4) {
        float4 ha = ((const float4*)hshA[w])[k4];   // wave-broadcast
        float4 hb = ((const float4*)hshB[w])[k4];
        float w0 = W2sh[(4 * k4 + 0) * 64 + lane];
        float w1 = W2sh[(4 * k4 + 1) * 64 + lane];
        float w2 = W2sh[(4 * k4 + 2) * 64 + lane];
        float w3 = W2sh[(4 * k4 + 3) * 64 + lane];
        acc2A = fmaf(ha.x, w0, acc2A); acc2B = fmaf(hb.x, w0, acc2B);
        acc2A = fmaf(ha.y, w1, acc2A); acc2B = fmaf(hb.y, w1, acc2B);
        acc2A = fmaf(ha.z, w2, acc2A); acc2B = fmaf(hb.z, w2, acc2B);
        acc2A = fmaf(ha.w, w3, acc2A); acc2B = fmaf(hb.w, w3, acc2B);
    }
    xs2[(size_t)nodeA * 64 + lane] = (feat_t)acc2A;
    xs2[(size_t)nodeB * 64 + lane] = (feat_t)acc2B;
    float psA = acc2A * avs2, pdA = acc2A * avd2;
    float psB = acc2B * avs2, pdB = acc2B * avd2;
    for (int off = 1; off < 16; off <<= 1) {
        psA += __shfl_xor(psA, off);
        pdA += __shfl_xor(pdA, off);
        psB += __shfl_xor(psB, off);
        pdB += __shfl_xor(pdB, off);
    }
    if ((lane & 15) == 0) {
        asrc2[nodeA * 4 + (lane >> 4)] = psA;
        adst2[nodeA * 4 + (lane >> 4)] = pdA;
        asrc2[nodeB * 4 + (lane >> 4)] = psB;
        adst2[nodeB * 4 + (lane >> 4)] = pdB;
    }
}

// ---------------- agg2 + fused mean-pool (R17/R7-proven, 2 chains) -----------
__global__ __launch_bounds__(256, 6) void agg2_kernel(const feat_t* __restrict__ xs,
                                                      const unsigned int* __restrict__ csr_se,
                                                      const int* __restrict__ degp,
                                                      const float* __restrict__ a_src,
                                                      const float* __restrict__ a_dst,
                                                      const float* __restrict__ wd,
                                                      const float* __restrict__ bias,
                                                      const int* __restrict__ batch,
                                                      float* __restrict__ gout) {
    __shared__ float plds[256];
    int t = threadIdx.x;
    int w = t >> 6, lane = t & 63;
    const int e_idx = lane >> 2;
    const int h4 = lane & 3;
    const int h2 = lane >> 4;
    int nodeA = blockIdx.x * 8 + w * 2;
    int nodeB = nodeA + 1;

    float wdv = wd[h4];
    float bv = bias[lane];
    float advA = a_dst[nodeA * 4 + h4];
    float advB = a_dst[nodeB * 4 + h4];
    int nA = min(degp[(size_t)nodeA * CSTRIDE], CAP);
    int nB = min(degp[(size_t)nodeB * CSTRIDE], CAP);
    int begA = nodeA * CAP, endA = begA + nA;
    int begB = nodeB * CAP, endB = begB + nB;

    float mA = -FLT_MAX, sA = 0.f, accA = 0.f;
    float mB = -FLT_MAX, sB = 0.f, accB = 0.f;

    auto alpha_phase = [&](int beg, int end, int it, float adv,
                           float& m, float& s, float& acc, int& sv, float& wgt) {
        int j = beg + it * 16 + e_idx;
        bool v = j < end;
        sv = 0;
        float a = -FLT_MAX;
        if (v) {
            unsigned int se = csr_se[j];
            sv = (int)(se & 0xFFFFu);
            float ea = __half2float(__ushort_as_half((unsigned short)(se >> 16)));
            float as = a_src[sv * 4 + h4];
            a = as + adv + ea * wdv;
            a = a > 0.f ? a : NEG_SLOPE * a;
        }
        float cm = a;
        cm = fmaxf(cm, __shfl_xor(cm, 4));
        cm = fmaxf(cm, __shfl_xor(cm, 8));
        cm = fmaxf(cm, __shfl_xor(cm, 16));
        cm = fmaxf(cm, __shfl_xor(cm, 32));
        float mn = fmaxf(m, cm);
        float sc = __expf(m - mn);
        wgt = __expf(a - mn);
        s = s * sc + wgt;
        m = mn;
        acc *= __shfl(sc, h2);
    };
    auto gather_phase = [&](int sv, float wgt, float& acc) {
#pragma unroll
        for (int e = 0; e < 16; ++e) {
            int svb = __builtin_amdgcn_readlane(sv, e << 2);
            float wg = __shfl(wgt, (e << 2) | h2);
            acc = fmaf(wg, (float)xs[(size_t)svb * 64 + lane], acc);
        }
    };

    int itA = (nA + 15) >> 4, itB = (nB + 15) >> 4;
    int itC = min(itA, itB);
    for (int it = 0; it < itC; ++it) {
        int svA, svB; float wgtA, wgtB;
        alpha_phase(begA, endA, it, advA, mA, sA, accA, svA, wgtA);
        alpha_phase(begB, endB, it, advB, mB, sB, accB, svB, wgtB);
        gather_phase(svA, wgtA, accA);
        gather_phase(svB, wgtB, accB);
    }
    for (int it = itC; it < itA; ++it) {
        int svA; float wgtA;
        alpha_phase(begA, endA, it, advA, mA, sA, accA, svA, wgtA);
        gather_phase(svA, wgtA, accA);
    }
    for (int it = itC; it < itB; ++it) {
        int svB; float wgtB;
        alpha_phase(begB, endB, it, advB, mB, sB, accB, svB, wgtB);
        gather_phase(svB, wgtB, accB);
    }

    auto finish = [&](float s, float acc) {
        s += __shfl_xor(s, 4);
        s += __shfl_xor(s, 8);
        s += __shfl_xor(s, 16);
        s += __shfl_xor(s, 32);
        float sh = __shfl(s, h2);
        float res = (sh > 0.f) ? acc / sh : 0.f;
        return res + bv;
    };
    float resA = finish(sA, accA);
    float resB = finish(sB, accB);

    int gA = batch[nodeA], gB = batch[nodeB];
    int gF = batch[blockIdx.x * 8];
    int gL = batch[blockIdx.x * 8 + 7];
    if (gF == gL) {                             // block-uniform branch
        plds[w * 64 + lane] = resA + resB;
        __syncthreads();
        if (w == 0) {
            float v = plds[lane] + plds[64 + lane] +
                      plds[128 + lane] + plds[192 + lane];
            atomicAdd(&gout[gF * 64 + lane], v);
        }
    } else {
        if (gA == gB) {
            atomicAdd(&gout[gA * 64 + lane], resA + resB);
        } else {
            atomicAdd(&gout[gA * 64 + lane], resA);
            atomicAdd(&gout[gB * 64 + lane], resB);
        }
    }
}

__global__ void pool_div_kernel(float* __restrict__ out, const int* __restrict__ batch) {
    int g = blockIdx.x, t = threadIdx.x;
    int lo = 0, hi = N_NODES;
    while (lo < hi) { int mid = (lo + hi) >> 1; if (batch[mid] < g) lo = mid + 1; else hi = mid; }
    int lo2 = lo, hi2 = N_NODES;
    while (lo2 < hi2) { int mid = (lo2 + hi2) >> 1; if (batch[mid] <= g) lo2 = mid + 1; else hi2 = mid; }
    float c = (float)max(lo2 - lo, 1);
    out[g * 64 + t] /= c;
}

// ---------------- launch ----------------

extern "C" void kernel_launch(void* const* d_in, const int* in_sizes, int n_in,
                              void* d_out, int out_size, void* d_ws, size_t ws_size,
                              hipStream_t stream) {
    const float* x    = (const float*)d_in[0];
    const int*   eidx = (const int*)d_in[1];
    const float* eat  = (const float*)d_in[2];
    const int*   batch= (const int*)d_in[3];
    const float* W1   = (const float*)d_in[4];
    const float* We1  = (const float*)d_in[5];
    const float* as1  = (const float*)d_in[6];
    const float* ad1  = (const float*)d_in[7];
    const float* ae1  = (const float*)d_in[8];
    const float* b1   = (const float*)d_in[9];
    const float* W2   = (const float*)d_in[10];
    const float* We2  = (const float*)d_in[11];
    const float* as2  = (const float*)d_in[12];
    const float* ad2  = (const float*)d_in[13];
    const float* ae2  = (const float*)d_in[14];
    const float* b2   = (const float*)d_in[15];
    const int* src  = eidx;             // edge_index[0]
    const int* dstp = eidx + N_EDGES;   // edge_index[1]
    float* out = (float*)d_out;

    char* p = (char*)d_ws;
    auto alloc = [&](size_t bytes) {
        char* r = p;
        p += (bytes + 255) & ~(size_t)255;
        return r;
    };
    unsigned int* csrse = (unsigned int*)alloc((size_t)N_NODES * CAP * 4);  // 12.8 MB
    feat_t* xs     = (feat_t*)alloc((size_t)N_NODES * 64 * 2);     // 6.4 MB fp16
    feat_t* hbuf   = (feat_t*)alloc((size_t)N_NODES * 64 * 2);     // 6.4 MB fp16
    float*  asrc   = (float*)alloc((size_t)N_NODES * 4 * 4);
    float*  adst   = (float*)alloc((size_t)N_NODES * 4 * 4);
    float*  asrc2  = (float*)alloc((size_t)N_NODES * 4 * 4);
    float*  adst2  = (float*)alloc((size_t)N_NODES * 4 * 4);
    float*  wd     = (float*)alloc(64);                            // wd1[4] || wd2[4]
    int*    cursor = (int*)alloc((size_t)N_NODES * CSTRIDE * 4);   // 3.2 MB padded

    hipMemsetAsync(cursor, 0, (size_t)N_NODES * CSTRIDE * 4, stream);

    const int NB = N_NODES / 8;                            // 6250 (×8 == N_NODES)

    // layer 1: fused transform + 3x-unrolled CSR scatter + rider (wedot + gout=0)
    fused1_kernel<<<FGRID, 256, 0, stream>>>(x, W1, as1, ad1, xs, asrc, adst,
                                             src, dstp, eat, cursor, csrse,
                                             We1, ae1, We2, ae2, wd, out);
    // aggregate layer 1 + fused layer-2 transform (R19 geometry, 2 chains)
    agg1_kernel<<<NB, 256, 0, stream>>>(xs, csrse, cursor, asrc, adst,
                                        wd, b1, W2, as2, ad2,
                                        hbuf, asrc2, adst2);
    // aggregate layer 2 + fused mean-pool (R17, 2 chains)
    agg2_kernel<<<NB, 256, 0, stream>>>(hbuf, csrse, cursor, asrc2, adst2,
                                        wd + 4, b2, batch, out);
    pool_div_kernel<<<N_GRAPHS, 64, 0, stream>>>(out, batch);
}